// Round 7
// baseline (5339.862 us; speedup 1.0000x reference)
//
#include <hip/hip_runtime.h>

#define NB    16      // batches
#define NPTS  100000  // points per batch
#define NCH   16      // channels
#define KSEL  1024    // samples
#define SLOTS 16      // blocks per batch
#define TPB   256     // threads per block
#define CHUNK 6250    // NPTS / SLOTS
#define PPT   25      // CHUNK / TPB (ceil)
#define MAGA  0x19u   // 5-bit magic, key word    (never 0, never 0xAA-pattern)
#define MAGB  0x13u   // 5-bit magic, payload words

typedef unsigned long long u64;
typedef unsigned int u32;
typedef __attribute__((ext_vector_type(4))) unsigned int u32x4;

// d_ws layout (bytes):
//   [4096, 135168)  : records u64[tier=2][par=2][NB][64 slots][4 words]
//                     tier 0 = fast (sc0 plain ops -> per-XCD L2)
//                     tier 1 = slow (agent-scope atomics -> device coherent)
//   [135168, 200704): idx list int[NB][KSEL]
//
// Record = 4 u64 words, 32B contiguous (one poll = 2x dwordx4):
//   word0 key = val_bits(32) | invidx(17) | tag(10) | MAGA(5)   (u64 max == winner)
//   word1..3  = coord_bits(32) | invidx(17) | tag(10) | MAGB(5)  (x,y,z)
// invidx = 131071 - idx  (max invidx == min idx -> first-index tie-break).
// tag = i+1 (never 0). Tag+magic in EVERY word -> stale/torn/poison self-
// rejecting; single writer per (slot,par,tag); values deterministic per
// (slot, iteration) -> even cross-replay stale data would be value-correct,
// and memset zeroes all records each launch anyway.

__device__ __forceinline__ void combine(float ov, int oi, float& v, int& i) {
  if (ov > v || (ov == v && oi < i)) { v = ov; i = oi; }
}

__global__ __launch_bounds__(TPB, 1)
void fps_kernel(const float* __restrict__ points, const int* __restrict__ start_idx,
                u64* __restrict__ ws_cand, int* __restrict__ ws_idx) {
  // XCD-affinity swizzle: all 16 blocks of a batch at raw%8==const -> (likely) one XCD.
  const int raw  = blockIdx.x;
  const int xcd  = raw & 7;
  const int s    = raw >> 3;
  const int b    = xcd + 8 * (s >> 4);
  const int slot = s & 15;

  const int tid  = threadIdx.x;
  const int lane = tid & 63;
  const int wid  = tid >> 6;
  const int sid  = (slot << 2) | wid;   // wave-level slot id, 0..63

  const int base = slot * CHUNK;
  const float* __restrict__ pb = points + (size_t)b * NPTS * NCH;

  // ---- load xyz into registers, init min_d ----
  float px[PPT], py[PPT], pz[PPT], md[PPT];
  #pragma unroll
  for (int k = 0; k < PPT; ++k) {
    const int li = tid + (k << 8);
    const bool valid = li < CHUNK;
    float4 p = make_float4(0.f, 0.f, 0.f, 0.f);
    if (valid) p = *reinterpret_cast<const float4*>(pb + (size_t)(base + li) * NCH);
    px[k] = p.x; py[k] = p.y; pz[k] = p.z;
    md[k] = valid ? __builtin_inff() : -__builtin_inff();
  }
  #pragma unroll
  for (int k = 0; k < PPT; ++k)   // keep-live guard against remat
    asm volatile("" : "+v"(px[k]), "+v"(py[k]), "+v"(pz[k]), "+v"(md[k]));

  // ---- initial selected point ----
  const int sidx = start_idx[b];
  float sx, sy, sz;
  {
    const float4 p = *reinterpret_cast<const float4*>(pb + (size_t)sidx * NCH);
    sx = p.x; sy = p.y; sz = p.z;
  }
  if (slot == 0 && tid == 0) ws_idx[b * KSEL] = sidx;

  for (int i = 0; i < KSEL - 1; ++i) {
    const int par = i & 1;
    u64* const fblk = ws_cand + (((size_t)par * NB + b) << 8);            // fast tier
    u64* const sblk = ws_cand + ((size_t)2 * NB << 8) + (((size_t)par * NB + b) << 8);

    // ---- distance update + thread-local argmax (bit-exact vs numpy f32:
    //      IEEE intrinsics, left-to-right sum, no FMA contraction) ----
    float bv = -__builtin_inff();
    int   bi = 0x7fffffff;
    #pragma unroll
    for (int k = 0; k < PPT; ++k) {
      const float dx = __fsub_rn(px[k], sx);
      const float dy = __fsub_rn(py[k], sy);
      const float dz = __fsub_rn(pz[k], sz);
      const float d  = __fadd_rn(__fadd_rn(__fmul_rn(dx, dx), __fmul_rn(dy, dy)),
                                 __fmul_rn(dz, dz));
      const float m  = fminf(md[k], d);
      md[k] = m;
      if (m > bv) { bv = m; bi = base + tid + (k << 8); }  // k asc -> first-max kept
    }

    // ---- wave reduce (val, idx), first-index tie-break; all lanes get result ----
    #pragma unroll
    for (int m = 32; m >= 1; m >>= 1) {
      const float ov = __shfl_xor(bv, m, 64);
      const int   oi = __shfl_xor(bi, m, 64);
      combine(ov, oi, bv, bi);
    }

    const u32 tm    = (u32)(i + 1) << 5;
    const u32 wantA = tm | MAGA;
    const u32 wantB = tm | MAGB;

    // ---- owner lane publishes wave record to BOTH tiers (no barriers) ----
    const int local = bi - base;
    if (lane == (local & 63)) {
      const int kk = local >> 8;
      float ox = 0.f, oy = 0.f, oz = 0.f;
      #pragma unroll
      for (int k = 0; k < PPT; ++k)   // static-index select (keeps arrays in VGPRs)
        if (k == kk) { ox = px[k]; oy = py[k]; oz = pz[k]; }
      const u32 inv  = 131071u - (u32)bi;
      const u32 keylo = (inv << 15) | wantA;
      const u32 meta  = (inv << 15) | wantB;
      u32x4 lo, hi;
      lo.x = keylo;               lo.y = __float_as_uint(bv);
      lo.z = meta;                lo.w = __float_as_uint(ox);
      hi.x = meta;                hi.y = __float_as_uint(oy);
      hi.z = meta;                hi.w = __float_as_uint(oz);
      u64* const frec = fblk + ((size_t)sid << 2);
      asm volatile("global_store_dwordx4 %0, %1, off sc0\n\t"
                   "global_store_dwordx4 %2, %3, off sc0"
                   :: "v"(frec), "v"(lo), "v"(frec + 2), "v"(hi) : "memory");
      u64* const srec = sblk + ((size_t)sid << 2);
      const u64 k64 = ((u64)__float_as_uint(bv) << 32) | keylo;
      __hip_atomic_store(srec + 0, k64, __ATOMIC_RELAXED, __HIP_MEMORY_SCOPE_AGENT);
      __hip_atomic_store(srec + 1, ((u64)__float_as_uint(ox) << 32) | meta, __ATOMIC_RELAXED, __HIP_MEMORY_SCOPE_AGENT);
      __hip_atomic_store(srec + 2, ((u64)__float_as_uint(oy) << 32) | meta, __ATOMIC_RELAXED, __HIP_MEMORY_SCOPE_AGENT);
      __hip_atomic_store(srec + 3, ((u64)__float_as_uint(oz) << 32) | meta, __ATOMIC_RELAXED, __HIP_MEMORY_SCOPE_AGENT);
    }

    // ---- poll: lane L owns slot L. TIGHT fast-tier loop (sc0 -> per-XCD L2);
    //      slow-tier correctness check only every 16th retry. ----
    u64* const prec = fblk + ((size_t)lane << 2);
    const u64* const qrec = sblk + ((size_t)lane << 2);
    u64 kcand; u32 xb, yb, zb;
    int r = 0;
    for (;;) {
      u32x4 lo, hi;
      asm volatile("global_load_dwordx4 %0, %2, off sc0\n\t"
                   "global_load_dwordx4 %1, %3, off sc0\n\t"
                   "s_waitcnt vmcnt(0)"
                   : "=&v"(lo), "=&v"(hi)
                   : "v"(prec), "v"(prec + 2)
                   : "memory");
      if ((lo.x & 0x7FFFu) == wantA && (lo.z & 0x7FFFu) == wantB &&
          (hi.x & 0x7FFFu) == wantB && (hi.z & 0x7FFFu) == wantB) {
        kcand = ((u64)lo.y << 32) | lo.x; xb = lo.w; yb = hi.y; zb = hi.w;
        break;
      }
      if ((++r & 15) == 0) {   // coherent fallback, correct for any XCD mapping
        const u64 a0 = __hip_atomic_load(qrec + 0, __ATOMIC_RELAXED, __HIP_MEMORY_SCOPE_AGENT);
        const u64 a1 = __hip_atomic_load(qrec + 1, __ATOMIC_RELAXED, __HIP_MEMORY_SCOPE_AGENT);
        const u64 a2 = __hip_atomic_load(qrec + 2, __ATOMIC_RELAXED, __HIP_MEMORY_SCOPE_AGENT);
        const u64 a3 = __hip_atomic_load(qrec + 3, __ATOMIC_RELAXED, __HIP_MEMORY_SCOPE_AGENT);
        if (((u32)a0 & 0x7FFFu) == wantA && ((u32)a1 & 0x7FFFu) == wantB &&
            ((u32)a2 & 0x7FFFu) == wantB && ((u32)a3 & 0x7FFFu) == wantB) {
          kcand = a0; xb = (u32)(a1 >> 32); yb = (u32)(a2 >> 32); zb = (u32)(a3 >> 32);
          break;
        }
      }
    }

    // ---- global winner: u64 max over 64 lanes; payload shuffled from winner lane ----
    u64 kmax = kcand;
    #pragma unroll
    for (int m = 32; m >= 1; m >>= 1) {
      const u64 o = __shfl_xor(kmax, m, 64);
      if (o > kmax) kmax = o;
    }
    const unsigned long long ball = __ballot(kcand == kmax);  // keys unique (distinct idx)
    const int wl = __ffsll(ball) - 1;
    sx = __uint_as_float((u32)__shfl((int)xb, wl, 64));
    sy = __uint_as_float((u32)__shfl((int)yb, wl, 64));
    sz = __uint_as_float((u32)__shfl((int)zb, wl, 64));

    if (slot == 0 && tid == 0)
      ws_idx[b * KSEL + i + 1] = 131071 - (int)((kmax >> 15) & 0x1FFFFu);
  }
}

__global__ void gather_kernel(const float* __restrict__ points,
                              const int* __restrict__ ws_idx,
                              float* __restrict__ out) {
  const int e = blockIdx.x * TPB + threadIdx.x;   // 0 .. NB*KSEL*NCH-1
  const int c = e & 15;
  const int k = (e >> 4) & (KSEL - 1);
  const int b = e >> 14;
  const int idx = ws_idx[b * KSEL + k];
  out[e] = points[((size_t)b * NPTS + idx) * NCH + c];
}

extern "C" void kernel_launch(void* const* d_in, const int* in_sizes, int n_in,
                              void* d_out, int out_size, void* d_ws, size_t ws_size,
                              hipStream_t stream) {
  const float* points    = (const float*)d_in[0];
  const int*   start_idx = (const int*)d_in[1];
  float*       out       = (float*)d_out;

  u64* cand = (u64*)((char*)d_ws + 4096);
  int* idxl = (int*)((char*)d_ws + 4096 + 131072);

  // all record words must start tag-invalid (0) every launch (graph-replay safe)
  hipMemsetAsync(cand, 0, 131072, stream);

  fps_kernel<<<NB * SLOTS, TPB, 0, stream>>>(points, start_idx, cand, idxl);
  gather_kernel<<<(NB * KSEL * NCH) / TPB, TPB, 0, stream>>>(points, idxl, out);
}

// Round 8
// 2870.484 us; speedup vs baseline: 1.8603x; 1.8603x over previous
//
#include <hip/hip_runtime.h>

#define NB    16      // batches
#define NPTS  100000  // points per batch
#define NCH   16      // channels
#define KSEL  1024    // samples
#define SLOTS 16      // blocks per batch
#define TPB   256     // threads per block
#define CHUNK 6250    // NPTS / SLOTS
#define PPT   25      // CHUNK / TPB
#define MAGA  0x19u   // 5-bit magic, key words    (never 0, never 0xAA-pattern)
#define MAGB  0x13u   // 5-bit magic, payload words

typedef unsigned long long u64;
typedef unsigned int u32;

// d_ws layout (bytes):
//   [4096, 20480)  : records u64[par=2][NB][word=4][slot=16]
//                    word 0 = keys line, 1/2/3 = x/y/z lines (128B each)
//   [65536, 131072): idx list int[NB][KSEL]
//
// key     = val_bits(32) | invidx(17) | tag(10) | MAGA(5)   (u64 max == winner)
// payload = coord_bits(32) | invidx(17) | tag(10) | MAGB(5)
// invidx = 131071 - idx (max invidx == min idx -> first-index tie-break).
// tag = i+1 (1..1023, never 0 -> memset-0 / 0xAA never match). Tag+magic in
// EVERY u64 -> stale/torn/poison self-rejecting. Single writer per
// (slot,parity,tag); parity double-buffer prevents i/i+2 overwrite (a slot can
// only advance 2 iterations after ALL slots consumed the current one).
// Contention design: ONE polling wave per block -> 16 pollers per line
// (was 64 in r5-r7); poll = 1 u64 agent load per lane covering all 4 lines.

__device__ __forceinline__ void combine(float ov, int oi, float& v, int& i) {
  if (ov > v || (ov == v && oi < i)) { v = ov; i = oi; }
}

__global__ __launch_bounds__(TPB, 1)
void fps_kernel(const float* __restrict__ points, const int* __restrict__ start_idx,
                u64* __restrict__ ws_cand, int* __restrict__ ws_idx) {
  // XCD-affinity swizzle: all 16 blocks of a batch at raw%8==const.
  const int raw  = blockIdx.x;
  const int xcd  = raw & 7;
  const int s    = raw >> 3;
  const int b    = xcd + 8 * (s >> 4);
  const int slot = s & 15;

  const int tid  = threadIdx.x;
  const int lane = tid & 63;
  const int wid  = tid >> 6;

  const int base = slot * CHUNK;
  const float* __restrict__ pb = points + (size_t)b * NPTS * NCH;

  // ---- load xyz into registers, init min_d ----
  float px[PPT], py[PPT], pz[PPT], md[PPT];
  #pragma unroll
  for (int k = 0; k < PPT; ++k) {
    const int li = tid + (k << 8);
    const bool valid = li < CHUNK;
    float4 p = make_float4(0.f, 0.f, 0.f, 0.f);
    if (valid) p = *reinterpret_cast<const float4*>(pb + (size_t)(base + li) * NCH);
    px[k] = p.x; py[k] = p.y; pz[k] = p.z;
    md[k] = valid ? __builtin_inff() : -__builtin_inff();
  }
  #pragma unroll
  for (int k = 0; k < PPT; ++k)   // keep-live guard
    asm volatile("" : "+v"(px[k]), "+v"(py[k]), "+v"(pz[k]), "+v"(md[k]));

  __shared__ float s_rv[4];    // per-wave candidates (written pre-b1, read post-b1)
  __shared__ int   s_ri[4];
  __shared__ float s_wx, s_wy, s_wz;  // winner broadcast (written pre-b2, read post-b2)

  // ---- initial selected point ----
  const int sidx = start_idx[b];
  float sx, sy, sz;
  {
    const float4 p = *reinterpret_cast<const float4*>(pb + (size_t)sidx * NCH);
    sx = p.x; sy = p.y; sz = p.z;
  }
  if (slot == 0 && tid == 0) ws_idx[b * KSEL] = sidx;

  for (int i = 0; i < KSEL - 1; ++i) {
    const int par = i & 1;
    u64* const blk = ws_cand + (((size_t)par * NB + b) << 6);  // 64 u64 per (par,b)

    // ---- distance update + thread-local argmax (bit-exact vs numpy f32:
    //      IEEE intrinsics, left-to-right sum, no FMA contraction) ----
    float bv = -__builtin_inff();
    int   bi = 0x7fffffff;
    #pragma unroll
    for (int k = 0; k < PPT; ++k) {
      const float dx = __fsub_rn(px[k], sx);
      const float dy = __fsub_rn(py[k], sy);
      const float dz = __fsub_rn(pz[k], sz);
      const float d  = __fadd_rn(__fadd_rn(__fmul_rn(dx, dx), __fmul_rn(dy, dy)),
                                 __fmul_rn(dz, dz));
      const float m  = fminf(md[k], d);
      md[k] = m;
      if (m > bv) { bv = m; bi = base + tid + (k << 8); }  // k asc -> first-max kept
    }

    // ---- wave reduce (val, idx), first-index tie-break ----
    #pragma unroll
    for (int m = 32; m >= 1; m >>= 1) {
      const float ov = __shfl_xor(bv, m, 64);
      const int   oi = __shfl_xor(bi, m, 64);
      combine(ov, oi, bv, bi);
    }
    if (lane == 0) { s_rv[wid] = bv; s_ri[wid] = bi; }
    __syncthreads();                                   // b1: candidates ready

    // ---- block combine (every thread) ----
    bv = s_rv[0]; bi = s_ri[0];
    #pragma unroll
    for (int w = 1; w < 4; ++w) combine(s_rv[w], s_ri[w], bv, bi);

    const u32 tm = (u32)(i + 1) << 5;

    // ---- owner thread publishes {key,x,y,z} to the 4 SoA lines ----
    const int local = bi - base;
    if (tid == (local & 255)) {
      const int kk = local >> 8;
      float ox = 0.f, oy = 0.f, oz = 0.f;
      #pragma unroll
      for (int k = 0; k < PPT; ++k)   // static-index select (arrays stay in VGPRs)
        if (k == kk) { ox = px[k]; oy = py[k]; oz = pz[k]; }
      const u32 inv  = 131071u - (u32)bi;
      const u32 loA  = (inv << 15) | tm | MAGA;
      const u32 loB  = (inv << 15) | tm | MAGB;
      __hip_atomic_store(blk      + slot, ((u64)__float_as_uint(bv) << 32) | loA,
                         __ATOMIC_RELAXED, __HIP_MEMORY_SCOPE_AGENT);
      __hip_atomic_store(blk + 16 + slot, ((u64)__float_as_uint(ox) << 32) | loB,
                         __ATOMIC_RELAXED, __HIP_MEMORY_SCOPE_AGENT);
      __hip_atomic_store(blk + 32 + slot, ((u64)__float_as_uint(oy) << 32) | loB,
                         __ATOMIC_RELAXED, __HIP_MEMORY_SCOPE_AGENT);
      __hip_atomic_store(blk + 48 + slot, ((u64)__float_as_uint(oz) << 32) | loB,
                         __ATOMIC_RELAXED, __HIP_MEMORY_SCOPE_AGENT);
    }

    // ---- wave 0 ONLY polls (16 pollers/line instead of 64) ----
    if (wid == 0) {
      const int wrd = lane >> 4;                 // 0=key,1=x,2=y,3=z
      const u64* const myp = blk + lane;         // [word][slot] layout: blk+lane
      const u32 want = tm | (wrd == 0 ? MAGA : MAGB);
      u64 q;
      for (;;) {
        q = __hip_atomic_load(myp, __ATOMIC_RELAXED, __HIP_MEMORY_SCOPE_AGENT);
        if (__all(((u32)q & 0x7FFFu) == want)) break;
        __builtin_amdgcn_s_sleep(1);
      }
      // max over the 16 key lanes (xor net stays within each 16-group)
      u64 key = q;
      #pragma unroll
      for (int m = 8; m >= 1; m >>= 1) {
        const u64 o = __shfl_xor(key, m, 64);
        if (o > key) key = o;
      }
      const u64 kmax = __shfl(key, 0, 64);       // true key max, broadcast
      const unsigned long long ball = __ballot(wrd == 0 && q == kmax);
      const int rs = __ffsll(ball) - 1;          // winning slot (keys unique)
      const u32 xb = (u32)__shfl((int)(u32)(q >> 32), 16 + rs, 64);
      const u32 yb = (u32)__shfl((int)(u32)(q >> 32), 32 + rs, 64);
      const u32 zb = (u32)__shfl((int)(u32)(q >> 32), 48 + rs, 64);
      if (lane == 0) {
        s_wx = __uint_as_float(xb);
        s_wy = __uint_as_float(yb);
        s_wz = __uint_as_float(zb);
        if (slot == 0)
          ws_idx[b * KSEL + i + 1] = 131071 - (int)((kmax >> 15) & 0x1FFFFu);
      }
    }
    __syncthreads();                                   // b2: winner ready
    sx = s_wx; sy = s_wy; sz = s_wz;
  }
}

__global__ void gather_kernel(const float* __restrict__ points,
                              const int* __restrict__ ws_idx,
                              float* __restrict__ out) {
  const int e = blockIdx.x * TPB + threadIdx.x;   // 0 .. NB*KSEL*NCH-1
  const int c = e & 15;
  const int k = (e >> 4) & (KSEL - 1);
  const int b = e >> 14;
  const int idx = ws_idx[b * KSEL + k];
  out[e] = points[((size_t)b * NPTS + idx) * NCH + c];
}

extern "C" void kernel_launch(void* const* d_in, const int* in_sizes, int n_in,
                              void* d_out, int out_size, void* d_ws, size_t ws_size,
                              hipStream_t stream) {
  const float* points    = (const float*)d_in[0];
  const int*   start_idx = (const int*)d_in[1];
  float*       out       = (float*)d_out;

  u64* cand = (u64*)((char*)d_ws + 4096);
  int* idxl = (int*)((char*)d_ws + 65536);

  // all record words must start tag-invalid (0) every launch (graph-replay safe)
  hipMemsetAsync(cand, 0, 2 * NB * 4 * SLOTS * sizeof(u64), stream);

  fps_kernel<<<NB * SLOTS, TPB, 0, stream>>>(points, start_idx, cand, idxl);
  gather_kernel<<<(NB * KSEL * NCH) / TPB, TPB, 0, stream>>>(points, idxl, out);
}